// Round 1
// baseline (392.359 us; speedup 1.0000x reference)
//
#include <hip/hip_runtime.h>
#include <hip/hip_bf16.h>

#define D_MODEL 1024
#define N_HEADS 16
#define DH      64
#define BATCH   2
#define SEQ     2048
#define M_ROWS  (BATCH*SEQ)   // 4096

using f32x4 = __attribute__((ext_vector_type(4))) float;
using bfx8  = __attribute__((ext_vector_type(8))) short;   // 8 bf16 in 4 VGPRs

__device__ __forceinline__ float bf2f(unsigned short u){
    unsigned int v = ((unsigned int)u) << 16;
    float f; __builtin_memcpy(&f, &v, 4); return f;
}
__device__ __forceinline__ unsigned short f2bf(float f){
    unsigned int u; __builtin_memcpy(&u, &f, 4);
    u = (u + 0x7FFFu + ((u >> 16) & 1u)) >> 16;   // RNE
    return (unsigned short)u;
}

typedef __attribute__((address_space(3))) void as3_void;
typedef __attribute__((address_space(1))) const void as1_cvoid;
__device__ __forceinline__ void gload16(const void* g, void* l){
    __builtin_amdgcn_global_load_lds((as1_cvoid*)g, (as3_void*)l, 16, 0, 0);
}

// ---------------- cast x (f32 -> bf16), 4 elems/thread ----------------
__global__ void cast_x_kernel(const float* __restrict__ x, unsigned short* __restrict__ xb){
    int i = blockIdx.x*blockDim.x + threadIdx.x;
    float4 v = reinterpret_cast<const float4*>(x)[i];
    ushort4 o; o.x=f2bf(v.x); o.y=f2bf(v.y); o.z=f2bf(v.z); o.w=f2bf(v.w);
    reinterpret_cast<ushort4*>(xb)[i] = o;
}

// ---------- cast+transpose weights: w[k][n] f32 -> wt[n][k] bf16 ----------
__global__ void transpose_cast_w(const float* __restrict__ w0, const float* __restrict__ w1,
                                 const float* __restrict__ w2, const float* __restrict__ w3,
                                 unsigned short* __restrict__ o0, unsigned short* __restrict__ o1,
                                 unsigned short* __restrict__ o2, unsigned short* __restrict__ o3){
    __shared__ float tile[32][33];
    const float* w; unsigned short* o;
    switch (blockIdx.z){
        case 0:  w=w0; o=o0; break;
        case 1:  w=w1; o=o1; break;
        case 2:  w=w2; o=o2; break;
        default: w=w3; o=o3; break;
    }
    const int tx = threadIdx.x, ty = threadIdx.y;
    const int x0 = blockIdx.x*32, y0 = blockIdx.y*32;
    #pragma unroll
    for (int j=0;j<32;j+=8) tile[ty+j][tx] = w[(size_t)(y0+ty+j)*D_MODEL + x0 + tx];
    __syncthreads();
    #pragma unroll
    for (int j=0;j<32;j+=8) o[(size_t)(x0+ty+j)*D_MODEL + y0 + tx] = f2bf(tile[tx][ty+j]);
}

// ---------------- RoPE in place on Q,K (bf16), 8 elems = 4 pairs / thread ----------------
__global__ void rope_kernel(unsigned short* __restrict__ q, unsigned short* __restrict__ k){
    const int id = blockIdx.x*blockDim.x + threadIdx.x;
    const int half = BATCH*SEQ*(D_MODEL/8);          // 524288 groups per tensor
    unsigned short* p = (id < half) ? q : k;
    const int i  = (id < half) ? id : id - half;
    const int gd = i & (D_MODEL/8 - 1);              // 8-elem group within row
    const int bt = i >> 7;                           // 0..4095
    const int t  = bt & (SEQ-1);
    unsigned short* base = p + (size_t)bt*D_MODEL + gd*8;
    uint4 raw = *reinterpret_cast<uint4*>(base);
    unsigned short e[8]; __builtin_memcpy(e, &raw, 16);
    const float cfac = -0.02595256269f;              // -log2(10000)/512
    #pragma unroll
    for (int u=0; u<4; ++u){
        int pi = gd*4 + u;                           // pair index in [0,512)
        float invf = exp2f(cfac * (float)pi);
        float ang  = (float)t * invf;
        float s, c; sincosf(ang, &s, &c);
        float a = bf2f(e[2*u]), b = bf2f(e[2*u+1]);
        e[2*u]   = f2bf(a*c - b*s);
        e[2*u+1] = f2bf(b*c + a*s);
    }
    __builtin_memcpy(&raw, e, 16);
    *reinterpret_cast<uint4*>(base) = raw;
}

// ---------------- GEMM: C[M=4096][N=1024] = A[M][K=1024] * Bt[N][K]^T ----------------
// MODE 0: write bf16 row-major.  MODE 1: write V transposed (B,H,DH,SEQ) bf16.  MODE 2: f32 row-major.
template<int MODE>
__global__ __launch_bounds__(256) void gemm_bf16(const unsigned short* __restrict__ A,
                                                 const unsigned short* __restrict__ Bt,
                                                 void* __restrict__ dst){
    __shared__ unsigned short As[128*32];
    __shared__ unsigned short Bs[128*32];
    const int tid = threadIdx.x;
    const int lane = tid & 63, wid = tid >> 6;
    const int l15 = lane & 15, hi = lane >> 4;
    const int wr = wid >> 1, wc = wid & 1;
    const int m0 = blockIdx.y * 128, n0 = blockIdx.x * 128;

    f32x4 acc[4][4] = {};

    for (int kt = 0; kt < D_MODEL; kt += 32){
        __syncthreads();
        #pragma unroll
        for (int i = 0; i < 2; ++i){
            int c = tid + 256*i;                      // 16B chunk id, 512 per tile
            const unsigned short* ga = A  + (size_t)(m0 + (c>>2))*D_MODEL + kt + (c&3)*8;
            gload16(ga, As + c*8);
            const unsigned short* gb = Bt + (size_t)(n0 + (c>>2))*D_MODEL + kt + (c&3)*8;
            gload16(gb, Bs + c*8);
        }
        asm volatile("s_waitcnt vmcnt(0)" ::: "memory");
        __syncthreads();
        bfx8 a[4], b[4];
        #pragma unroll
        for (int t = 0; t < 4; ++t){
            a[t] = *reinterpret_cast<const bfx8*>(As + (64*wr + 16*t + l15)*32 + 8*hi);
            b[t] = *reinterpret_cast<const bfx8*>(Bs + (64*wc + 16*t + l15)*32 + 8*hi);
        }
        #pragma unroll
        for (int rt = 0; rt < 4; ++rt)
            #pragma unroll
            for (int ct = 0; ct < 4; ++ct)
                acc[rt][ct] = __builtin_amdgcn_mfma_f32_16x16x32_bf16(a[rt], b[ct], acc[rt][ct], 0, 0, 0);
    }

    #pragma unroll
    for (int rt = 0; rt < 4; ++rt)
        #pragma unroll
        for (int ct = 0; ct < 4; ++ct){
            const int m = m0 + 64*wr + 16*rt + 4*hi;     // +r
            const int n = n0 + 64*wc + 16*ct + l15;
            if (MODE == 0){
                unsigned short* o = (unsigned short*)dst;
                #pragma unroll
                for (int r=0;r<4;++r) o[(size_t)(m+r)*D_MODEL + n] = f2bf(acc[rt][ct][r]);
            } else if (MODE == 1){
                const int b  = m >> 11, t = m & (SEQ-1);
                const int h  = n >> 6,  d = n & 63;
                ushort4 pk;
                pk.x = f2bf(acc[rt][ct][0]); pk.y = f2bf(acc[rt][ct][1]);
                pk.z = f2bf(acc[rt][ct][2]); pk.w = f2bf(acc[rt][ct][3]);
                unsigned short* o = (unsigned short*)dst;
                *reinterpret_cast<ushort4*>(o + ((size_t)((b*N_HEADS + h)*DH + d))*SEQ + t) = pk;
            } else {
                float* o = (float*)dst;
                #pragma unroll
                for (int r=0;r<4;++r) o[(size_t)(m+r)*D_MODEL + n] = acc[rt][ct][r];
            }
        }
}

// ---------------- causal flash attention ----------------
// grid (SEQ/64, N_HEADS, BATCH), 256 threads (4 waves), wave w owns q rows [q0+16w, q0+16w+16)
__global__ __launch_bounds__(256) void attn_kernel(const unsigned short* __restrict__ Q,
                                                   const unsigned short* __restrict__ K,
                                                   const unsigned short* __restrict__ Vt,
                                                   unsigned short* __restrict__ O){
    __shared__ unsigned short P_lds[4][16*64];
    const int tid = threadIdx.x, lane = tid & 63, wid = tid >> 6;
    const int l15 = lane & 15, hi = lane >> 4;
    const int b = blockIdx.z, h = blockIdx.y, q0 = blockIdx.x * 64;
    const int qr = q0 + wid*16;

    bfx8 qf[2];
    {
        const unsigned short* qp = Q + ((size_t)(b*SEQ) + qr + l15)*D_MODEL + h*DH + 8*hi;
        qf[0] = *reinterpret_cast<const bfx8*>(qp);
        qf[1] = *reinterpret_cast<const bfx8*>(qp + 32);
    }
    f32x4 oacc[4] = {};
    float m_r[4], l_r[4];
    #pragma unroll
    for (int r=0;r<4;++r){ m_r[r] = -1e30f; l_r[r] = 0.f; }

    for (int kk0 = 0; kk0 <= q0; kk0 += 64){
        // S = Q K^T (16 x 64 per wave)
        f32x4 sa[4];
        #pragma unroll
        for (int nt=0; nt<4; ++nt){
            const unsigned short* kp = K + ((size_t)(b*SEQ) + kk0 + nt*16 + l15)*D_MODEL + h*DH + 8*hi;
            bfx8 k0 = *reinterpret_cast<const bfx8*>(kp);
            bfx8 k1 = *reinterpret_cast<const bfx8*>(kp + 32);
            f32x4 z = {};
            z = __builtin_amdgcn_mfma_f32_16x16x32_bf16(qf[0], k0, z, 0,0,0);
            z = __builtin_amdgcn_mfma_f32_16x16x32_bf16(qf[1], k1, z, 0,0,0);
            sa[nt] = z;
        }
        const bool diag = (kk0 == q0);
        float s[4][4];
        #pragma unroll
        for (int nt=0;nt<4;++nt)
            #pragma unroll
            for (int r=0;r<4;++r){
                float v = sa[nt][r] * 0.125f;        // 1/sqrt(64)
                if (diag){
                    int col = kk0 + nt*16 + l15;
                    int row = qr + 4*hi + r;
                    if (col > row) v = -1e30f;
                }
                s[nt][r] = v;
            }
        float mnew[4], alpha[4];
        #pragma unroll
        for (int r=0;r<4;++r){
            float mx = fmaxf(fmaxf(s[0][r], s[1][r]), fmaxf(s[2][r], s[3][r]));
            mx = fmaxf(mx, __shfl_xor(mx, 1));
            mx = fmaxf(mx, __shfl_xor(mx, 2));
            mx = fmaxf(mx, __shfl_xor(mx, 4));
            mx = fmaxf(mx, __shfl_xor(mx, 8));
            mnew[r] = fmaxf(m_r[r], mx);
            alpha[r] = __expf(m_r[r] - mnew[r]);
            m_r[r] = mnew[r];
        }
        #pragma unroll
        for (int r=0;r<4;++r){
            float rs = 0.f;
            #pragma unroll
            for (int nt=0;nt<4;++nt){
                float p = __expf(s[nt][r] - mnew[r]);
                rs += p;
                P_lds[wid][(4*hi + r)*64 + nt*16 + l15] = f2bf(p);
            }
            rs += __shfl_xor(rs, 1);
            rs += __shfl_xor(rs, 2);
            rs += __shfl_xor(rs, 4);
            rs += __shfl_xor(rs, 8);
            l_r[r] = l_r[r]*alpha[r] + rs;
        }
        asm volatile("s_waitcnt lgkmcnt(0)" ::: "memory");
        bfx8 pa[2];
        pa[0] = *reinterpret_cast<const bfx8*>(&P_lds[wid][l15*64 + 8*hi]);
        pa[1] = *reinterpret_cast<const bfx8*>(&P_lds[wid][l15*64 + 32 + 8*hi]);
        #pragma unroll
        for (int dt=0; dt<4; ++dt){
            f32x4 o = oacc[dt];
            #pragma unroll
            for (int r=0;r<4;++r) o[r] *= alpha[r];
            const unsigned short* vp = Vt + ((size_t)((b*N_HEADS + h)*DH) + dt*16 + l15)*SEQ + kk0 + 8*hi;
            bfx8 v0 = *reinterpret_cast<const bfx8*>(vp);
            bfx8 v1 = *reinterpret_cast<const bfx8*>(vp + 32);
            o = __builtin_amdgcn_mfma_f32_16x16x32_bf16(pa[0], v0, o, 0,0,0);
            o = __builtin_amdgcn_mfma_f32_16x16x32_bf16(pa[1], v1, o, 0,0,0);
            oacc[dt] = o;
        }
    }
    #pragma unroll
    for (int dt=0;dt<4;++dt){
        float inv_l[4];
        #pragma unroll
        for (int r=0;r<4;++r) inv_l[r] = 1.0f / l_r[r];
        #pragma unroll
        for (int r=0;r<4;++r){
            int row = qr + 4*hi + r;
            O[((size_t)(b*SEQ) + row)*D_MODEL + h*DH + dt*16 + l15] = f2bf(oacc[dt][r] * inv_l[r]);
        }
    }
}

extern "C" void kernel_launch(void* const* d_in, const int* in_sizes, int n_in,
                              void* d_out, int out_size, void* d_ws, size_t ws_size,
                              hipStream_t stream) {
    const float* x  = (const float*)d_in[0];
    // d_in[1] = causal mask (bool) — deterministic tril, regenerated implicitly, unused
    const float* wq = (const float*)d_in[2];
    const float* wk = (const float*)d_in[3];
    const float* wv = (const float*)d_in[4];
    const float* wo = (const float*)d_in[5];

    char* ws = (char*)d_ws;
    unsigned short* xb  = (unsigned short*)(ws);                     // 8 MB
    unsigned short* wqt = (unsigned short*)(ws + (8u  << 20));       // 2 MB each
    unsigned short* wkt = (unsigned short*)(ws + (10u << 20));
    unsigned short* wvt = (unsigned short*)(ws + (12u << 20));
    unsigned short* wot = (unsigned short*)(ws + (14u << 20));
    unsigned short* Qb  = (unsigned short*)(ws + (16u << 20));       // 8 MB
    unsigned short* Kb  = (unsigned short*)(ws + (24u << 20));       // 8 MB
    unsigned short* Vt  = (unsigned short*)(ws + (32u << 20));       // 8 MB (B,H,DH,SEQ)
    unsigned short* Ob  = (unsigned short*)(ws + (40u << 20));       // 8 MB

    cast_x_kernel<<<M_ROWS*D_MODEL/4/256, 256, 0, stream>>>(x, xb);
    transpose_cast_w<<<dim3(32,32,4), dim3(32,8), 0, stream>>>(wq,wk,wv,wo, wqt,wkt,wvt,wot);

    gemm_bf16<0><<<dim3(8,32), 256, 0, stream>>>(xb, wqt, Qb);
    gemm_bf16<0><<<dim3(8,32), 256, 0, stream>>>(xb, wkt, Kb);
    gemm_bf16<1><<<dim3(8,32), 256, 0, stream>>>(xb, wvt, Vt);

    rope_kernel<<<2*M_ROWS*(D_MODEL/8)/256, 256, 0, stream>>>(Qb, Kb);

    attn_kernel<<<dim3(SEQ/64, N_HEADS, BATCH), 256, 0, stream>>>(Qb, Kb, Vt, Ob);

    gemm_bf16<2><<<dim3(8,32), 256, 0, stream>>>(Ob, wot, d_out);
}

// Round 2
// 224.624 us; speedup vs baseline: 1.7467x; 1.7467x over previous
//
#include <hip/hip_runtime.h>
#include <hip/hip_bf16.h>

#define D_MODEL 1024
#define N_HEADS 16
#define DH      64
#define BATCH   2
#define SEQ     2048
#define M_ROWS  (BATCH*SEQ)   // 4096

#define QB   128              // q rows per block (32 per wave)
#define KVB  64               // k/v tile
#define NQT  (SEQ/QB)         // 16

using f32x4 = __attribute__((ext_vector_type(4))) float;
using bfx8  = __attribute__((ext_vector_type(8))) short;   // 8 bf16 in 4 VGPRs

__device__ __forceinline__ float bf2f(unsigned short u){
    unsigned int v = ((unsigned int)u) << 16;
    float f; __builtin_memcpy(&f, &v, 4); return f;
}
__device__ __forceinline__ unsigned short f2bf(float f){
    unsigned int u; __builtin_memcpy(&u, &f, 4);
    u = (u + 0x7FFFu + ((u >> 16) & 1u)) >> 16;   // RNE
    return (unsigned short)u;
}

typedef __attribute__((address_space(3))) void as3_void;
typedef __attribute__((address_space(1))) const void as1_cvoid;
__device__ __forceinline__ void gload16(const void* g, void* l){
    __builtin_amdgcn_global_load_lds((as1_cvoid*)g, (as3_void*)l, 16, 0, 0);
}

// ---------------- cast x (f32 -> bf16), 4 elems/thread ----------------
__global__ void cast_x_kernel(const float* __restrict__ x, unsigned short* __restrict__ xb){
    int i = blockIdx.x*blockDim.x + threadIdx.x;
    float4 v = reinterpret_cast<const float4*>(x)[i];
    ushort4 o; o.x=f2bf(v.x); o.y=f2bf(v.y); o.z=f2bf(v.z); o.w=f2bf(v.w);
    reinterpret_cast<ushort4*>(xb)[i] = o;
}

// ---------- cast+transpose weights: w[k][n] f32 -> wt[n][k] bf16 ----------
__global__ void transpose_cast_w(const float* __restrict__ w0, const float* __restrict__ w1,
                                 const float* __restrict__ w2, const float* __restrict__ w3,
                                 unsigned short* __restrict__ o0, unsigned short* __restrict__ o1,
                                 unsigned short* __restrict__ o2, unsigned short* __restrict__ o3){
    __shared__ float tile[32][33];
    const float* w; unsigned short* o;
    switch (blockIdx.z){
        case 0:  w=w0; o=o0; break;
        case 1:  w=w1; o=o1; break;
        case 2:  w=w2; o=o2; break;
        default: w=w3; o=o3; break;
    }
    const int tx = threadIdx.x, ty = threadIdx.y;
    const int x0 = blockIdx.x*32, y0 = blockIdx.y*32;
    #pragma unroll
    for (int j=0;j<32;j+=8) tile[ty+j][tx] = w[(size_t)(y0+ty+j)*D_MODEL + x0 + tx];
    __syncthreads();
    #pragma unroll
    for (int j=0;j<32;j+=8) o[(size_t)(x0+ty+j)*D_MODEL + y0 + tx] = f2bf(tile[tx][ty+j]);
}

// ---------------- RoPE in place on Q,K (bf16), 8 elems = 4 pairs / thread ----------------
__global__ void rope_kernel(unsigned short* __restrict__ q, unsigned short* __restrict__ k){
    const int id = blockIdx.x*blockDim.x + threadIdx.x;
    const int half = BATCH*SEQ*(D_MODEL/8);          // 524288 groups per tensor
    unsigned short* p = (id < half) ? q : k;
    const int i  = (id < half) ? id : id - half;
    const int gd = i & (D_MODEL/8 - 1);              // 8-elem group within row
    const int bt = i >> 7;                           // 0..4095
    const int t  = bt & (SEQ-1);
    unsigned short* base = p + (size_t)bt*D_MODEL + gd*8;
    uint4 raw = *reinterpret_cast<uint4*>(base);
    unsigned short e[8]; __builtin_memcpy(e, &raw, 16);
    const float cfac = -0.02595256269f;              // -log2(10000)/512
    #pragma unroll
    for (int u=0; u<4; ++u){
        int pi = gd*4 + u;                           // pair index in [0,512)
        float invf = exp2f(cfac * (float)pi);
        float ang  = (float)t * invf;
        float s, c; sincosf(ang, &s, &c);
        float a = bf2f(e[2*u]), b = bf2f(e[2*u+1]);
        e[2*u]   = f2bf(a*c - b*s);
        e[2*u+1] = f2bf(b*c + a*s);
    }
    __builtin_memcpy(&raw, e, 16);
    *reinterpret_cast<uint4*>(base) = raw;
}

// ---------------- GEMM: C[M=4096][N=1024] = A[M][K=1024] * Bt[N][K]^T ----------------
// MODE 0: write bf16 row-major.  MODE 1: write V transposed (B,H,DH,SEQ) bf16.  MODE 2: f32 row-major.
template<int MODE>
__global__ __launch_bounds__(256) void gemm_bf16(const unsigned short* __restrict__ A,
                                                 const unsigned short* __restrict__ Bt,
                                                 void* __restrict__ dst){
    __shared__ unsigned short As[128*32];
    __shared__ unsigned short Bs[128*32];
    const int tid = threadIdx.x;
    const int lane = tid & 63, wid = tid >> 6;
    const int l15 = lane & 15, hi = lane >> 4;
    const int wr = wid >> 1, wc = wid & 1;
    const int m0 = blockIdx.y * 128, n0 = blockIdx.x * 128;

    f32x4 acc[4][4] = {};

    for (int kt = 0; kt < D_MODEL; kt += 32){
        __syncthreads();
        #pragma unroll
        for (int i = 0; i < 2; ++i){
            int c = tid + 256*i;                      // 16B chunk id, 512 per tile
            const unsigned short* ga = A  + (size_t)(m0 + (c>>2))*D_MODEL + kt + (c&3)*8;
            gload16(ga, As + c*8);
            const unsigned short* gb = Bt + (size_t)(n0 + (c>>2))*D_MODEL + kt + (c&3)*8;
            gload16(gb, Bs + c*8);
        }
        asm volatile("s_waitcnt vmcnt(0)" ::: "memory");
        __syncthreads();
        bfx8 a[4], b[4];
        #pragma unroll
        for (int t = 0; t < 4; ++t){
            a[t] = *reinterpret_cast<const bfx8*>(As + (64*wr + 16*t + l15)*32 + 8*hi);
            b[t] = *reinterpret_cast<const bfx8*>(Bs + (64*wc + 16*t + l15)*32 + 8*hi);
        }
        #pragma unroll
        for (int rt = 0; rt < 4; ++rt)
            #pragma unroll
            for (int ct = 0; ct < 4; ++ct)
                acc[rt][ct] = __builtin_amdgcn_mfma_f32_16x16x32_bf16(a[rt], b[ct], acc[rt][ct], 0, 0, 0);
    }

    #pragma unroll
    for (int rt = 0; rt < 4; ++rt)
        #pragma unroll
        for (int ct = 0; ct < 4; ++ct){
            const int m = m0 + 64*wr + 16*rt + 4*hi;     // +r
            const int n = n0 + 64*wc + 16*ct + l15;
            if (MODE == 0){
                unsigned short* o = (unsigned short*)dst;
                #pragma unroll
                for (int r=0;r<4;++r) o[(size_t)(m+r)*D_MODEL + n] = f2bf(acc[rt][ct][r]);
            } else if (MODE == 1){
                const int b  = m >> 11, t = m & (SEQ-1);
                const int h  = n >> 6,  d = n & 63;
                ushort4 pk;
                pk.x = f2bf(acc[rt][ct][0]); pk.y = f2bf(acc[rt][ct][1]);
                pk.z = f2bf(acc[rt][ct][2]); pk.w = f2bf(acc[rt][ct][3]);
                unsigned short* o = (unsigned short*)dst;
                *reinterpret_cast<ushort4*>(o + ((size_t)((b*N_HEADS + h)*DH + d))*SEQ + t) = pk;
            } else {
                float* o = (float*)dst;
                #pragma unroll
                for (int r=0;r<4;++r) o[(size_t)(m+r)*D_MODEL + n] = acc[rt][ct][r];
            }
        }
}

// ======================= causal flash attention v2 ==========================
// grid (NQT, N_HEADS, BATCH), 256 threads (4 waves). Block owns 128 q rows
// (wave w: rows [Q0+32w, Q0+32w+32)). K/V tiles (KVB=64) staged in LDS,
// double-buffered, XOR-swizzled (16B chunk ^ (row&7)); P via per-wave LDS.
// ===========================================================================

// stage one K tile (rows kk0..+63 of K[b], cols h*DH..+64) and one V tile
// (Vt rows (b,h,dh 0..63), cols kk0..+63) into swizzled LDS buffers.
__device__ __forceinline__ void stage_kv(const unsigned short* __restrict__ Kg,   // K + (b*SEQ+kk0)*D_MODEL + h*DH
                                         const unsigned short* __restrict__ Vg,   // Vt + ((b*NH+h)*DH)*SEQ + kk0
                                         unsigned short* kl, unsigned short* vl, int tid){
    #pragma unroll
    for (int i=0;i<2;++i){
        int cid = tid + 256*i;                 // 0..511 : row=cid>>3, chunk=cid&7
        int row = cid >> 3, c = cid & 7;
        int sc = c ^ (row & 7);                // pre-swizzled global source
        gload16(Kg + (size_t)row*D_MODEL + sc*8, kl + cid*8);
    }
    #pragma unroll
    for (int i=0;i<2;++i){
        int cid = tid + 256*i;
        int row = cid >> 3, c = cid & 7;
        int sc = c ^ (row & 7);
        gload16(Vg + (size_t)row*SEQ + sc*8, vl + cid*8);
    }
}

__global__ __launch_bounds__(256, 2) void attn_kernel(const unsigned short* __restrict__ Q,
                                                      const unsigned short* __restrict__ K,
                                                      const unsigned short* __restrict__ Vt,
                                                      unsigned short* __restrict__ O){
    __shared__ unsigned short Kl[2][KVB*DH];       // [64 k-rows][64 dh], swizzled
    __shared__ unsigned short Vl[2][DH*KVB];       // [64 dh-rows][64 seq], swizzled
    __shared__ unsigned short Pl[4][32*KVB];       // per-wave [32 q][64 k], swizzled

    const int tid = threadIdx.x, lane = tid & 63, wid = tid >> 6;
    const int l15 = lane & 15, hi = lane >> 4;
    const int b = blockIdx.z, h = blockIdx.y;
    const int qi = (NQT - 1) - blockIdx.x;          // longest-first
    const int Q0 = qi * QB;
    const int nkt = 2*qi + 2;                       // k-tiles to cover rows [Q0, Q0+127]

    const unsigned short* Kbase = K  + (size_t)(b*SEQ)*D_MODEL + h*DH;
    const unsigned short* Vbase = Vt + ((size_t)((b*N_HEADS + h)*DH))*SEQ;

    // Q fragments: rows Q0 + wid*32 + ib*16 + l15, k = 32*ks + 8*hi
    bfx8 qf[2][2];
    #pragma unroll
    for (int ib=0; ib<2; ++ib){
        const unsigned short* qp = Q + ((size_t)(b*SEQ) + Q0 + wid*32 + ib*16 + l15)*D_MODEL + h*DH + 8*hi;
        qf[ib][0] = *reinterpret_cast<const bfx8*>(qp);
        qf[ib][1] = *reinterpret_cast<const bfx8*>(qp + 32);
    }

    f32x4 oacc[2][4] = {};
    float m_r[2][4], l_r[2][4], alpha[2][4];
    #pragma unroll
    for (int ib=0;ib<2;++ib)
        #pragma unroll
        for (int r=0;r<4;++r){ m_r[ib][r] = -1e30f; l_r[ib][r] = 0.f; }

    stage_kv(Kbase, Vbase, Kl[0], Vl[0], tid);      // prologue: tile 0 -> buf 0

    for (int t = 0; t < nkt; ++t){
        const int cur = t & 1;
        const int kk0 = t * KVB;
        __syncthreads();                            // all waves done reading buf[(t+1)&1]
        if (t + 1 < nkt){
            const int kn = (t+1) * KVB;
            stage_kv(Kbase + (size_t)kn*D_MODEL, Vbase + kn, Kl[cur^1], Vl[cur^1], tid);
            asm volatile("s_waitcnt vmcnt(4)" ::: "memory");   // cur-tile loads done, next in flight
        } else {
            asm volatile("s_waitcnt vmcnt(0)" ::: "memory");
        }
        __syncthreads();                            // cur buf visible to all waves

        // ---- S = Q K^T : per wave 32x64 ----
        bfx8 kf[4][2];
        #pragma unroll
        for (int nt=0; nt<4; ++nt){
            int row = nt*16 + l15;
            #pragma unroll
            for (int ks=0; ks<2; ++ks){
                int ch = (4*ks + hi) ^ (row & 7);
                kf[nt][ks] = *reinterpret_cast<const bfx8*>(&Kl[cur][row*64 + ch*8]);
            }
        }
        f32x4 sa[2][4];
        #pragma unroll
        for (int ib=0; ib<2; ++ib)
            #pragma unroll
            for (int nt=0; nt<4; ++nt){
                f32x4 z = {};
                z = __builtin_amdgcn_mfma_f32_16x16x32_bf16(qf[ib][0], kf[nt][0], z, 0,0,0);
                z = __builtin_amdgcn_mfma_f32_16x16x32_bf16(qf[ib][1], kf[nt][1], z, 0,0,0);
                sa[ib][nt] = z;
            }

        // ---- scale + causal mask ----
        float s[2][4][4];
        #pragma unroll
        for (int ib=0; ib<2; ++ib){
            const int rmin = Q0 + wid*32 + ib*16;
            const bool dm = (kk0 + KVB - 1) > rmin;
            #pragma unroll
            for (int nt=0; nt<4; ++nt)
                #pragma unroll
                for (int r=0; r<4; ++r){
                    float v = sa[ib][nt][r] * 0.125f;      // 1/sqrt(64)
                    if (dm){
                        int col = kk0 + nt*16 + l15;
                        int row = rmin + 4*hi + r;
                        if (col > row) v = -1e30f;
                    }
                    s[ib][nt][r] = v;
                }
        }

        // ---- online softmax: row max / rescale / exp / row sum; P -> LDS ----
        #pragma unroll
        for (int ib=0; ib<2; ++ib)
            #pragma unroll
            for (int r=0; r<4; ++r){
                float mx = fmaxf(fmaxf(s[ib][0][r], s[ib][1][r]), fmaxf(s[ib][2][r], s[ib][3][r]));
                mx = fmaxf(mx, __shfl_xor(mx, 1));
                mx = fmaxf(mx, __shfl_xor(mx, 2));
                mx = fmaxf(mx, __shfl_xor(mx, 4));
                mx = fmaxf(mx, __shfl_xor(mx, 8));
                float mnew = fmaxf(m_r[ib][r], mx);
                alpha[ib][r] = __expf(m_r[ib][r] - mnew);
                m_r[ib][r] = mnew;
            }
        #pragma unroll
        for (int ib=0; ib<2; ++ib)
            #pragma unroll
            for (int r=0; r<4; ++r){
                const int rl = ib*16 + 4*hi + r;            // local q row
                float rs = 0.f;
                #pragma unroll
                for (int nt=0; nt<4; ++nt){
                    float p = __expf(s[ib][nt][r] - m_r[ib][r]);
                    rs += p;
                    int col = nt*16 + l15;
                    Pl[wid][rl*64 + (((col>>3) ^ (rl&7))<<3) + (col&7)] = f2bf(p);
                }
                rs += __shfl_xor(rs, 1);
                rs += __shfl_xor(rs, 2);
                rs += __shfl_xor(rs, 4);
                rs += __shfl_xor(rs, 8);
                l_r[ib][r] = l_r[ib][r]*alpha[ib][r] + rs;
            }

        // ---- O = P V : per wave 32x64 ----
        bfx8 vf[4][2], pa[2][2];
        #pragma unroll
        for (int dt=0; dt<4; ++dt){
            int row = dt*16 + l15;
            #pragma unroll
            for (int ks=0; ks<2; ++ks){
                int ch = (4*ks + hi) ^ (row & 7);
                vf[dt][ks] = *reinterpret_cast<const bfx8*>(&Vl[cur][row*64 + ch*8]);
            }
        }
        #pragma unroll
        for (int ib=0; ib<2; ++ib){
            int row = ib*16 + l15;
            #pragma unroll
            for (int ks=0; ks<2; ++ks){
                int ch = (4*ks + hi) ^ (row & 7);
                pa[ib][ks] = *reinterpret_cast<const bfx8*>(&Pl[wid][row*64 + ch*8]);
            }
        }
        #pragma unroll
        for (int ib=0; ib<2; ++ib)
            #pragma unroll
            for (int dt=0; dt<4; ++dt){
                f32x4 o = oacc[ib][dt];
                #pragma unroll
                for (int r=0;r<4;++r) o[r] *= alpha[ib][r];
                o = __builtin_amdgcn_mfma_f32_16x16x32_bf16(pa[ib][0], vf[dt][0], o, 0,0,0);
                o = __builtin_amdgcn_mfma_f32_16x16x32_bf16(pa[ib][1], vf[dt][1], o, 0,0,0);
                oacc[ib][dt] = o;
            }
    }

    // ---- epilogue: normalize and store ----
    #pragma unroll
    for (int ib=0; ib<2; ++ib)
        #pragma unroll
        for (int r=0; r<4; ++r){
            float invl = 1.0f / l_r[ib][r];
            int row = Q0 + wid*32 + ib*16 + 4*hi + r;
            #pragma unroll
            for (int dt=0; dt<4; ++dt)
                O[((size_t)(b*SEQ) + row)*D_MODEL + h*DH + dt*16 + l15] = f2bf(oacc[ib][dt][r] * invl);
        }
}

extern "C" void kernel_launch(void* const* d_in, const int* in_sizes, int n_in,
                              void* d_out, int out_size, void* d_ws, size_t ws_size,
                              hipStream_t stream) {
    const float* x  = (const float*)d_in[0];
    // d_in[1] = causal mask (bool) — deterministic tril, unused
    const float* wq = (const float*)d_in[2];
    const float* wk = (const float*)d_in[3];
    const float* wv = (const float*)d_in[4];
    const float* wo = (const float*)d_in[5];

    char* ws = (char*)d_ws;
    unsigned short* xb  = (unsigned short*)(ws);                     // 8 MB
    unsigned short* wqt = (unsigned short*)(ws + (8u  << 20));       // 2 MB each
    unsigned short* wkt = (unsigned short*)(ws + (10u << 20));
    unsigned short* wvt = (unsigned short*)(ws + (12u << 20));
    unsigned short* wot = (unsigned short*)(ws + (14u << 20));
    unsigned short* Qb  = (unsigned short*)(ws + (16u << 20));       // 8 MB
    unsigned short* Kb  = (unsigned short*)(ws + (24u << 20));       // 8 MB
    unsigned short* Vt  = (unsigned short*)(ws + (32u << 20));       // 8 MB (B,H,DH,SEQ)
    unsigned short* Ob  = (unsigned short*)(ws + (40u << 20));       // 8 MB

    cast_x_kernel<<<M_ROWS*D_MODEL/4/256, 256, 0, stream>>>(x, xb);
    transpose_cast_w<<<dim3(32,32,4), dim3(32,8), 0, stream>>>(wq,wk,wv,wo, wqt,wkt,wvt,wot);

    gemm_bf16<0><<<dim3(8,32), 256, 0, stream>>>(xb, wqt, Qb);
    gemm_bf16<0><<<dim3(8,32), 256, 0, stream>>>(xb, wkt, Kb);
    gemm_bf16<1><<<dim3(8,32), 256, 0, stream>>>(xb, wvt, Vt);

    rope_kernel<<<2*M_ROWS*(D_MODEL/8)/256, 256, 0, stream>>>(Qb, Kb);

    attn_kernel<<<dim3(NQT, N_HEADS, BATCH), 256, 0, stream>>>(Qb, Kb, Vt, Ob);

    gemm_bf16<2><<<dim3(8,32), 256, 0, stream>>>(Ob, wot, d_out);
}

// Round 4
// 148.517 us; speedup vs baseline: 2.6418x; 1.5124x over previous
//
#include <hip/hip_runtime.h>
#include <hip/hip_bf16.h>

#define D_MODEL 1024
#define N_HEADS 16
#define DH      64
#define BATCH   2
#define SEQ     2048
#define M_ROWS  (BATCH*SEQ)   // 4096

#define QB   128              // q rows per block (32 per wave, 4 waves)
#define KVB  64               // k/v tile
#define NQT  (SEQ/QB)         // 16

using f32x4  = __attribute__((ext_vector_type(4)))  float;
using f32x16 = __attribute__((ext_vector_type(16))) float;
using bfx8   = __attribute__((ext_vector_type(8)))  short;   // 8 bf16 in 4 VGPRs

__device__ __forceinline__ float bf2f(unsigned short u){
    unsigned int v = ((unsigned int)u) << 16;
    float f; __builtin_memcpy(&f, &v, 4); return f;
}
__device__ __forceinline__ unsigned short f2bf(float f){
    unsigned int u; __builtin_memcpy(&u, &f, 4);
    u = (u + 0x7FFFu + ((u >> 16) & 1u)) >> 16;   // RNE
    return (unsigned short)u;
}
__device__ __forceinline__ unsigned int cvtpk_bf16(float lo, float hi){
    unsigned int r;
    asm("v_cvt_pk_bf16_f32 %0, %1, %2" : "=v"(r) : "v"(lo), "v"(hi));
    return r;
}

typedef __attribute__((address_space(3))) void as3_void;
typedef __attribute__((address_space(1))) const void as1_cvoid;
__device__ __forceinline__ void gload16(const void* g, void* l){
    __builtin_amdgcn_global_load_lds((as1_cvoid*)g, (as3_void*)l, 16, 0, 0);
}

// ---------------- cast x (f32 -> bf16), 4 elems/thread ----------------
__global__ void cast_x_kernel(const float* __restrict__ x, unsigned short* __restrict__ xb){
    int i = blockIdx.x*blockDim.x + threadIdx.x;
    float4 v = reinterpret_cast<const float4*>(x)[i];
    ushort4 o; o.x=f2bf(v.x); o.y=f2bf(v.y); o.z=f2bf(v.z); o.w=f2bf(v.w);
    reinterpret_cast<ushort4*>(xb)[i] = o;
}

// ---------- cast+transpose weights: w[k][n] f32 -> wt[n][k] bf16 ----------
__global__ void transpose_cast_w(const float* __restrict__ w0, const float* __restrict__ w1,
                                 const float* __restrict__ w2, const float* __restrict__ w3,
                                 unsigned short* __restrict__ o0, unsigned short* __restrict__ o1,
                                 unsigned short* __restrict__ o2, unsigned short* __restrict__ o3){
    __shared__ float tile[32][33];
    const float* w; unsigned short* o;
    switch (blockIdx.z){
        case 0:  w=w0; o=o0; break;
        case 1:  w=w1; o=o1; break;
        case 2:  w=w2; o=o2; break;
        default: w=w3; o=o3; break;
    }
    const int tx = threadIdx.x, ty = threadIdx.y;
    const int x0 = blockIdx.x*32, y0 = blockIdx.y*32;
    #pragma unroll
    for (int j=0;j<32;j+=8) tile[ty+j][tx] = w[(size_t)(y0+ty+j)*D_MODEL + x0 + tx];
    __syncthreads();
    #pragma unroll
    for (int j=0;j<32;j+=8) o[(size_t)(x0+ty+j)*D_MODEL + y0 + tx] = f2bf(tile[tx][ty+j]);
}

// ---------------- RoPE in place on Q,K (bf16), 8 elems = 4 pairs / thread ----------------
__global__ void rope_kernel(unsigned short* __restrict__ q, unsigned short* __restrict__ k){
    const int id = blockIdx.x*blockDim.x + threadIdx.x;
    const int half = BATCH*SEQ*(D_MODEL/8);          // 524288 groups per tensor
    unsigned short* p = (id < half) ? q : k;
    const int i  = (id < half) ? id : id - half;
    const int gd = i & (D_MODEL/8 - 1);              // 8-elem group within row
    const int bt = i >> 7;                           // 0..4095
    const int t  = bt & (SEQ-1);
    unsigned short* base = p + (size_t)bt*D_MODEL + gd*8;
    uint4 raw = *reinterpret_cast<uint4*>(base);
    unsigned short e[8]; __builtin_memcpy(e, &raw, 16);
    const float cfac = -0.02595256269f;              // -log2(10000)/512
    #pragma unroll
    for (int u=0; u<4; ++u){
        int pi = gd*4 + u;                           // pair index in [0,512)
        float invf = exp2f(cfac * (float)pi);
        float ang  = (float)t * invf;
        float s, c; sincosf(ang, &s, &c);
        float a = bf2f(e[2*u]), b = bf2f(e[2*u+1]);
        e[2*u]   = f2bf(a*c - b*s);
        e[2*u+1] = f2bf(b*c + a*s);
    }
    __builtin_memcpy(&raw, e, 16);
    *reinterpret_cast<uint4*>(base) = raw;
}

// ======== merged QKV GEMM: 3x C[4096][1024] = A * Wt^T, one launch =========
// blockIdx.x in [0,24): sel = x>>3 picks {Q,K,V}; V written transposed (B,H,DH,SEQ).
__global__ __launch_bounds__(256) void gemm_qkv(const unsigned short* __restrict__ A,
                                                const unsigned short* __restrict__ Bq,
                                                const unsigned short* __restrict__ Bk,
                                                const unsigned short* __restrict__ Bv,
                                                unsigned short* __restrict__ Qo,
                                                unsigned short* __restrict__ Ko,
                                                unsigned short* __restrict__ Vto){
    __shared__ unsigned short As[128*32];
    __shared__ unsigned short Bs[128*32];
    const int sel = blockIdx.x >> 3;
    const int n0  = (blockIdx.x & 7) * 128;
    const unsigned short* Bt = (sel==0) ? Bq : ((sel==1) ? Bk : Bv);
    const int tid = threadIdx.x;
    const int lane = tid & 63, wid = tid >> 6;
    const int l15 = lane & 15, hi = lane >> 4;
    const int wr = wid >> 1, wc = wid & 1;
    const int m0 = blockIdx.y * 128;

    f32x4 acc[4][4] = {};

    for (int kt = 0; kt < D_MODEL; kt += 32){
        __syncthreads();
        #pragma unroll
        for (int i = 0; i < 2; ++i){
            int c = tid + 256*i;
            const unsigned short* ga = A  + (size_t)(m0 + (c>>2))*D_MODEL + kt + (c&3)*8;
            gload16(ga, As + c*8);
            const unsigned short* gb = Bt + (size_t)(n0 + (c>>2))*D_MODEL + kt + (c&3)*8;
            gload16(gb, Bs + c*8);
        }
        asm volatile("s_waitcnt vmcnt(0)" ::: "memory");
        __syncthreads();
        bfx8 a[4], b[4];
        #pragma unroll
        for (int t = 0; t < 4; ++t){
            a[t] = *reinterpret_cast<const bfx8*>(As + (64*wr + 16*t + l15)*32 + 8*hi);
            b[t] = *reinterpret_cast<const bfx8*>(Bs + (64*wc + 16*t + l15)*32 + 8*hi);
        }
        #pragma unroll
        for (int rt = 0; rt < 4; ++rt)
            #pragma unroll
            for (int ct = 0; ct < 4; ++ct)
                acc[rt][ct] = __builtin_amdgcn_mfma_f32_16x16x32_bf16(a[rt], b[ct], acc[rt][ct], 0, 0, 0);
    }

    #pragma unroll
    for (int rt = 0; rt < 4; ++rt)
        #pragma unroll
        for (int ct = 0; ct < 4; ++ct){
            const int m = m0 + 64*wr + 16*rt + 4*hi;
            const int n = n0 + 64*wc + 16*ct + l15;
            if (sel < 2){
                unsigned short* o = sel ? Ko : Qo;
                #pragma unroll
                for (int r=0;r<4;++r) o[(size_t)(m+r)*D_MODEL + n] = f2bf(acc[rt][ct][r]);
            } else {
                const int b  = m >> 11, t = m & (SEQ-1);
                const int h  = n >> 6,  d = n & 63;
                ushort4 pk;
                pk.x = f2bf(acc[rt][ct][0]); pk.y = f2bf(acc[rt][ct][1]);
                pk.z = f2bf(acc[rt][ct][2]); pk.w = f2bf(acc[rt][ct][3]);
                *reinterpret_cast<ushort4*>(Vto + ((size_t)((b*N_HEADS + h)*DH + d))*SEQ + t) = pk;
            }
        }
}

// ---------------- final GEMM: f32 out ----------------
__global__ __launch_bounds__(256) void gemm_out(const unsigned short* __restrict__ A,
                                                const unsigned short* __restrict__ Bt,
                                                float* __restrict__ dst){
    __shared__ unsigned short As[128*32];
    __shared__ unsigned short Bs[128*32];
    const int tid = threadIdx.x;
    const int lane = tid & 63, wid = tid >> 6;
    const int l15 = lane & 15, hi = lane >> 4;
    const int wr = wid >> 1, wc = wid & 1;
    const int m0 = blockIdx.y * 128, n0 = blockIdx.x * 128;

    f32x4 acc[4][4] = {};

    for (int kt = 0; kt < D_MODEL; kt += 32){
        __syncthreads();
        #pragma unroll
        for (int i = 0; i < 2; ++i){
            int c = tid + 256*i;
            const unsigned short* ga = A  + (size_t)(m0 + (c>>2))*D_MODEL + kt + (c&3)*8;
            gload16(ga, As + c*8);
            const unsigned short* gb = Bt + (size_t)(n0 + (c>>2))*D_MODEL + kt + (c&3)*8;
            gload16(gb, Bs + c*8);
        }
        asm volatile("s_waitcnt vmcnt(0)" ::: "memory");
        __syncthreads();
        bfx8 a[4], b[4];
        #pragma unroll
        for (int t = 0; t < 4; ++t){
            a[t] = *reinterpret_cast<const bfx8*>(As + (64*wr + 16*t + l15)*32 + 8*hi);
            b[t] = *reinterpret_cast<const bfx8*>(Bs + (64*wc + 16*t + l15)*32 + 8*hi);
        }
        #pragma unroll
        for (int rt = 0; rt < 4; ++rt)
            #pragma unroll
            for (int ct = 0; ct < 4; ++ct)
                acc[rt][ct] = __builtin_amdgcn_mfma_f32_16x16x32_bf16(a[rt], b[ct], acc[rt][ct], 0, 0, 0);
    }

    #pragma unroll
    for (int rt = 0; rt < 4; ++rt)
        #pragma unroll
        for (int ct = 0; ct < 4; ++ct){
            const int m = m0 + 64*wr + 16*rt + 4*hi;
            const int n = n0 + 64*wc + 16*ct + l15;
            #pragma unroll
            for (int r=0;r<4;++r) dst[(size_t)(m+r)*D_MODEL + n] = acc[rt][ct][r];
        }
}

// ======================= causal flash attention v3 ==========================
// 1D grid of 512 blocks; decode pairs qi with 15-qi on the same CU slot.
// 4 waves x 32 q-rows. Swapped 32x32 QK^T -> P in registers (q = lane&31),
// in-register softmax (2 shuffles/tile), cvt_pk + shfl_xor(32) builds PV
// A-fragments. K/V in swizzled LDS, double-buffered, counted vmcnt.
// ===========================================================================
__device__ __forceinline__ void stage_kv(const unsigned short* __restrict__ Kg,
                                         const unsigned short* __restrict__ Vg,
                                         unsigned short* kl, unsigned short* vl, int tid){
    #pragma unroll
    for (int i=0;i<2;++i){
        int cid = tid + 256*i;                 // row=cid>>3, chunk=cid&7
        int row = cid >> 3, c = cid & 7;
        int sc = c ^ (row & 7);                // pre-swizzled global source
        gload16(Kg + (size_t)row*D_MODEL + sc*8, kl + cid*8);
    }
    #pragma unroll
    for (int i=0;i<2;++i){
        int cid = tid + 256*i;
        int row = cid >> 3, c = cid & 7;
        int sc = c ^ (row & 7);
        gload16(Vg + (size_t)row*SEQ + sc*8, vl + cid*8);
    }
}

__global__ __launch_bounds__(256, 2) void attn_kernel(const unsigned short* __restrict__ Q,
                                                      const unsigned short* __restrict__ K,
                                                      const unsigned short* __restrict__ Vt,
                                                      unsigned short* __restrict__ O){
    __shared__ unsigned short Kl[2][KVB*DH];       // [64 k-rows][64 dh], swizzled
    __shared__ unsigned short Vl[2][DH*KVB];       // [64 dh-rows][64 seq], swizzled

    const int tid = threadIdx.x, lane = tid & 63, wid = tid >> 6;
    const int l31 = lane & 31, hi2 = lane >> 5;
    // block decode: pair qi=k with qi=15-k on the same CU slot (i and i+256)
    const int i  = blockIdx.x;
    const int b  = i >> 8;
    const int rr = i & 255;
    const int h  = rr >> 4;
    const int kk = rr & 15;
    const int qi = b ? (15 - kk) : kk;
    const int Q0 = qi * QB;
    const int nkt = 2*qi + 2;
    const int qrow = Q0 + wid*32 + l31;            // this lane's q row

    const unsigned short* Kbase = K  + (size_t)(b*SEQ)*D_MODEL + h*DH;
    const unsigned short* Vbase = Vt + ((size_t)((b*N_HEADS + h)*DH))*SEQ;

    // Q fragments (B-operand): qf[m] = Q[qrow][16m + 8*hi2 .. +8]
    bfx8 qf[4];
    {
        const unsigned short* qp = Q + ((size_t)(b*SEQ) + qrow)*D_MODEL + h*DH + 8*hi2;
        #pragma unroll
        for (int m=0;m<4;++m) qf[m] = *reinterpret_cast<const bfx8*>(qp + 16*m);
    }

    f32x16 oacc[2] = {};
    float m_r = -1e30f, l_r = 0.f;

    stage_kv(Kbase, Vbase, Kl[0], Vl[0], tid);

    for (int t = 0; t < nkt; ++t){
        const int cur = t & 1;
        const int kk0 = t * KVB;
        __syncthreads();
        if (t + 1 < nkt){
            const int kn = (t+1) * KVB;
            stage_kv(Kbase + (size_t)kn*D_MODEL, Vbase + kn, Kl[cur^1], Vl[cur^1], tid);
            asm volatile("s_waitcnt vmcnt(4)" ::: "memory");
        } else {
            asm volatile("s_waitcnt vmcnt(0)" ::: "memory");
        }
        __syncthreads();

        const bool active = kk0 <= Q0 + wid*32 + 31;   // wave-uniform
        if (active){
            // ---- S^T = K Q^T : 2 k-subtiles of 32, each 32x32 over dh=64 ----
            f32x16 st[2];
            __builtin_amdgcn_s_setprio(1);
            #pragma unroll
            for (int kt=0; kt<2; ++kt){
                f32x16 z = {};
                #pragma unroll
                for (int m=0; m<4; ++m){
                    const int row = 32*kt + l31;
                    const int ch  = (2*m + hi2) ^ (row & 7);
                    bfx8 kf = *reinterpret_cast<const bfx8*>(&Kl[cur][row*64 + ch*8]);
                    z = __builtin_amdgcn_mfma_f32_32x32x16_bf16(kf, qf[m], z, 0, 0, 0);
                }
                st[kt] = z;
            }
            __builtin_amdgcn_s_setprio(0);

            // ---- scale + causal mask + row max (in-register) ----
            const bool needmask = (kk0 + KVB - 1) > (Q0 + wid*32);   // wave-uniform
            float p[2][16];
            float pm = -1e30f;
            #pragma unroll
            for (int kt=0; kt<2; ++kt)
                #pragma unroll
                for (int r=0; r<16; ++r){
                    float v = st[kt][r] * 0.125f;          // 1/sqrt(64)
                    if (needmask){
                        int kg = kk0 + 32*kt + (r&3) + 8*(r>>2) + 4*hi2;
                        if (kg > qrow) v = -1e30f;
                    }
                    p[kt][r] = v;
                    pm = fmaxf(pm, v);
                }
            pm = fmaxf(pm, __shfl_xor(pm, 32));

            // ---- defer-max rescale (T13) ----
            if (__any(pm - m_r > 8.f)){
                float mnew  = fmaxf(m_r, pm);
                float alpha = __expf(m_r - mnew);
                m_r = mnew;
                l_r *= alpha;
                #pragma unroll
                for (int r=0; r<16; ++r){
                    float ac = __shfl(alpha, (r&3) + 8*(r>>2) + 4*hi2);
                    oacc[0][r] *= ac;
                    oacc[1][r] *= ac;
                }
            }

            // ---- exp + row sum ----
            float rs = 0.f;
            #pragma unroll
            for (int kt=0; kt<2; ++kt)
                #pragma unroll
                for (int r=0; r<16; ++r){
                    float e = __expf(p[kt][r] - m_r);
                    p[kt][r] = e;
                    rs += e;
                }
            rs += __shfl_xor(rs, 32);
            l_r += rs;

            // ---- pack P -> PV A-fragments (cvt_pk + cross-half shfl) ----
            bfx8 pa[4];
            #pragma unroll
            for (int kt=0; kt<2; ++kt){
                unsigned int c[8], x[8];
                #pragma unroll
                for (int j=0; j<8; ++j) c[j] = cvtpk_bf16(p[kt][2*j], p[kt][2*j+1]);
                #pragma unroll
                for (int j=0; j<8; ++j) x[j] = __shfl_xor(c[j], 32);
                uint4 w0, w1;
                if (hi2 == 0){
                    w0 = make_uint4(c[0], c[1], x[0], x[1]);
                    w1 = make_uint4(c[4], c[5], x[4], x[5]);
                } else {
                    w0 = make_uint4(x[2], x[3], c[2], c[3]);
                    w1 = make_uint4(x[6], x[7], c[6], c[7]);
                }
                pa[2*kt]   = *reinterpret_cast<bfx8*>(&w0);
                pa[2*kt+1] = *reinterpret_cast<bfx8*>(&w1);
            }

            // ---- O += P V : 2 d-tiles x 4 k-slots ----
            __builtin_amdgcn_s_setprio(1);
            #pragma unroll
            for (int dt=0; dt<2; ++dt){
                f32x16 o = oacc[dt];
                #pragma unroll
                for (int ks=0; ks<4; ++ks){
                    const int row = 32*dt + l31;
                    const int ch  = (2*ks + hi2) ^ (row & 7);
                    bfx8 vf = *reinterpret_cast<const bfx8*>(&Vl[cur][row*64 + ch*8]);
                    o = __builtin_amdgcn_mfma_f32_32x32x16_bf16(pa[ks], vf, o, 0, 0, 0);
                }
                oacc[dt] = o;
            }
            __builtin_amdgcn_s_setprio(0);
        }
    }

    // ---- epilogue: normalize and store ----
    float inv = 1.0f / l_r;
    #pragma unroll
    for (int r=0; r<16; ++r){
        const int crow = (r&3) + 8*(r>>2) + 4*hi2;
        float ic = __shfl(inv, crow);
        const int row = Q0 + wid*32 + crow;
        #pragma unroll
        for (int dt=0; dt<2; ++dt)
            O[((size_t)(b*SEQ) + row)*D_MODEL + h*DH + 32*dt + l31] = f2bf(oacc[dt][r] * ic);
    }
}

extern "C" void kernel_launch(void* const* d_in, const int* in_sizes, int n_in,
                              void* d_out, int out_size, void* d_ws, size_t ws_size,
                              hipStream_t stream) {
    const float* x  = (const float*)d_in[0];
    // d_in[1] = causal mask (bool) — deterministic tril, unused
    const float* wq = (const float*)d_in[2];
    const float* wk = (const float*)d_in[3];
    const float* wv = (const float*)d_in[4];
    const float* wo = (const float*)d_in[5];

    char* ws = (char*)d_ws;
    unsigned short* xb  = (unsigned short*)(ws);                     // 8 MB
    unsigned short* wqt = (unsigned short*)(ws + (8u  << 20));       // 2 MB each
    unsigned short* wkt = (unsigned short*)(ws + (10u << 20));
    unsigned short* wvt = (unsigned short*)(ws + (12u << 20));
    unsigned short* wot = (unsigned short*)(ws + (14u << 20));
    unsigned short* Qb  = (unsigned short*)(ws + (16u << 20));       // 8 MB
    unsigned short* Kb  = (unsigned short*)(ws + (24u << 20));       // 8 MB
    unsigned short* Vt  = (unsigned short*)(ws + (32u << 20));       // 8 MB (B,H,DH,SEQ)
    unsigned short* Ob  = (unsigned short*)(ws + (40u << 20));       // 8 MB

    cast_x_kernel<<<M_ROWS*D_MODEL/4/256, 256, 0, stream>>>(x, xb);
    transpose_cast_w<<<dim3(32,32,4), dim3(32,8), 0, stream>>>(wq,wk,wv,wo, wqt,wkt,wvt,wot);

    gemm_qkv<<<dim3(24,32), 256, 0, stream>>>(xb, wqt, wkt, wvt, Qb, Kb, Vt);

    rope_kernel<<<2*M_ROWS*(D_MODEL/8)/256, 256, 0, stream>>>(Qb, Kb);

    attn_kernel<<<512, 256, 0, stream>>>(Qb, Kb, Vt, Ob);

    gemm_out<<<dim3(8,32), 256, 0, stream>>>(Ob, wot, (float*)d_out);
}